// Round 2
// baseline (2502.781 us; speedup 1.0000x reference)
//
#include <hip/hip_runtime.h>

#define D 4096
#define RANK 1024
#define NTOT 16777216  // 4^12 = D*D

// Small tables live in module __device__ globals, NOT d_ws (d_ws is exactly
// 4 planes = 256 MiB; anything past it faults).
__device__ float g_m2re[256];
__device__ float g_m2im[256];
__device__ float g_inv_tr[1];

// ---------------------------------------------------------------------------
// GEMM: rho = U U^H (complex), U = 4096x1024, from separate re/im planes.
// rho_re[a][b] = sum_r Ure[a,r]*Ure[b,r] + Uim[a,r]*Uim[b,r]
// rho_im[a][b] = sum_r Uim[a,r]*Ure[b,r] - Ure[a,r]*Uim[b,r]
// 64x64 tile per 256-thread block, each thread 4x4 outputs, K-tile 32.
// LDS layout transposed [k][row] (pad 68) so fragment loads are ds_read_b128.
// ---------------------------------------------------------------------------
__global__ __launch_bounds__(256) void gemm_rho(const float* __restrict__ Ure,
                                                const float* __restrict__ Uim,
                                                float* __restrict__ rho_re,
                                                float* __restrict__ rho_im)
{
    __shared__ __align__(16) float As_re[32][68];
    __shared__ __align__(16) float As_im[32][68];
    __shared__ __align__(16) float Bs_re[32][68];
    __shared__ __align__(16) float Bs_im[32][68];

    const int tx = threadIdx.x & 15, ty = threadIdx.x >> 4;
    const int row0 = blockIdx.y << 6, col0 = blockIdx.x << 6;
    const int lr = threadIdx.x >> 2;        // 0..63 : row within tile
    const int lk = (threadIdx.x & 3) << 2;  // 0,4,8,12 : k offset

    float cre[4][4] = {}, cim[4][4] = {};

    for (int kt = 0; kt < RANK; kt += 32) {
        #pragma unroll
        for (int h = 0; h < 2; ++h) {
            const int k = lk + h * 16;
            const float4 a_re = *(const float4*)&Ure[(size_t)(row0 + lr) * RANK + kt + k];
            const float4 a_im = *(const float4*)&Uim[(size_t)(row0 + lr) * RANK + kt + k];
            const float4 b_re = *(const float4*)&Ure[(size_t)(col0 + lr) * RANK + kt + k];
            const float4 b_im = *(const float4*)&Uim[(size_t)(col0 + lr) * RANK + kt + k];
            As_re[k + 0][lr] = a_re.x; As_re[k + 1][lr] = a_re.y;
            As_re[k + 2][lr] = a_re.z; As_re[k + 3][lr] = a_re.w;
            As_im[k + 0][lr] = a_im.x; As_im[k + 1][lr] = a_im.y;
            As_im[k + 2][lr] = a_im.z; As_im[k + 3][lr] = a_im.w;
            Bs_re[k + 0][lr] = b_re.x; Bs_re[k + 1][lr] = b_re.y;
            Bs_re[k + 2][lr] = b_re.z; Bs_re[k + 3][lr] = b_re.w;
            Bs_im[k + 0][lr] = b_im.x; Bs_im[k + 1][lr] = b_im.y;
            Bs_im[k + 2][lr] = b_im.z; Bs_im[k + 3][lr] = b_im.w;
        }
        __syncthreads();

        #pragma unroll 8
        for (int k = 0; k < 32; ++k) {
            const float4 ar4 = *(const float4*)&As_re[k][ty << 2];
            const float4 ai4 = *(const float4*)&As_im[k][ty << 2];
            const float4 br4 = *(const float4*)&Bs_re[k][tx << 2];
            const float4 bi4 = *(const float4*)&Bs_im[k][tx << 2];
            const float ar[4] = {ar4.x, ar4.y, ar4.z, ar4.w};
            const float ai[4] = {ai4.x, ai4.y, ai4.z, ai4.w};
            const float br[4] = {br4.x, br4.y, br4.z, br4.w};
            const float bi[4] = {bi4.x, bi4.y, bi4.z, bi4.w};
            #pragma unroll
            for (int i = 0; i < 4; ++i)
                #pragma unroll
                for (int j = 0; j < 4; ++j) {
                    cre[i][j] += ar[i] * br[j] + ai[i] * bi[j];
                    cim[i][j] += ai[i] * br[j] - ar[i] * bi[j];
                }
        }
        __syncthreads();
    }

    #pragma unroll
    for (int i = 0; i < 4; ++i) {
        const int row = row0 + (ty << 2) + i;
        float4 vre = {cre[i][0], cre[i][1], cre[i][2], cre[i][3]};
        float4 vim = {cim[i][0], cim[i][1], cim[i][2], cim[i][3]};
        *(float4*)&rho_re[(size_t)row * D + col0 + (tx << 2)] = vre;
        *(float4*)&rho_im[(size_t)row * D + col0 + (tx << 2)] = vim;
    }
}

// ---------------------------------------------------------------------------
// inverse trace of rho (trace is real: sum of diagonal of rho_re)
// ---------------------------------------------------------------------------
__global__ void trace_inv(const float* __restrict__ rho_re)
{
    __shared__ float red[256];
    float s = 0.f;
    for (int d = threadIdx.x; d < D; d += 256)
        s += rho_re[(size_t)d * (D + 1)];
    red[threadIdx.x] = s;
    __syncthreads();
    for (int off = 128; off > 0; off >>= 1) {
        if (threadIdx.x < off) red[threadIdx.x] += red[threadIdx.x + off];
        __syncthreads();
    }
    if (threadIdx.x == 0) g_inv_tr[0] = 1.0f / red[0];
}

// ---------------------------------------------------------------------------
// Fused 2-qubit measurement table: M2[s2][i2][j2] = M[sa][ia][ja]*M[sb][ib][jb]
// s2 = 4*sa+sb, i2 = 2*ia+ib, j2 = 2*ja+jb (complex product). 256 entries.
// ---------------------------------------------------------------------------
__global__ void build_m2(const float* __restrict__ Mre, const float* __restrict__ Mim)
{
    const int tid = threadIdx.x;  // 0..255 == s2*16 + i2*4 + j2
    const int s2 = tid >> 4, t2 = tid & 15;
    const int i2 = t2 >> 2, j2 = t2 & 3;
    const int sa = s2 >> 2, sb = s2 & 3;
    const int ia = i2 >> 1, ib = i2 & 1;
    const int ja = j2 >> 1, jb = j2 & 1;
    const float ar = Mre[sa * 4 + ia * 2 + ja], ai = Mim[sa * 4 + ia * 2 + ja];
    const float br = Mre[sb * 4 + ib * 2 + jb], bi = Mim[sb * 4 + ib * 2 + jb];
    g_m2re[tid] = ar * br - ai * bi;
    g_m2im[tid] = ar * bi + ai * br;
}

// ---------------------------------------------------------------------------
// One fused 2-qubit contraction pass.
// Input  T [k, 4(j2), Rq, 4(i2), Cq]  (complex, separate planes)
// Output T'[k*16 + s2, Rq, Cq],  T'(k,s2,a,t) = sum_{i2,j2} M2[s2,i2,j2]*T(k,j2,a,i2,t)
// Cq = Rq = 1<<cqb. 2^20 threads, each handles one (k,a,t): 16 cplx in, 16 out.
// ---------------------------------------------------------------------------
__global__ __launch_bounds__(256) void qmt_pass(const float* __restrict__ in_re,
                                                const float* __restrict__ in_im,
                                                float* __restrict__ out_re,
                                                float* __restrict__ out_im,
                                                const int cqb)
{
    // stage m2 into LDS once per block
    __shared__ float m2re_s[256], m2im_s[256];
    m2re_s[threadIdx.x] = g_m2re[threadIdx.x];
    m2im_s[threadIdx.x] = g_m2im[threadIdx.x];
    __syncthreads();

    const int tid = blockIdx.x * 256 + threadIdx.x;
    const int Cq = 1 << cqb;
    const int t = tid & (Cq - 1);
    const int a = (tid >> cqb) & (Cq - 1);
    const int k = tid >> (2 * cqb);
    const int base = k << (4 + 2 * cqb);  // k * 16 * Cq^2
    const int CqX4 = Cq << 2;

    float xre[4][4], xim[4][4];
    #pragma unroll
    for (int j2 = 0; j2 < 4; ++j2)
        #pragma unroll
        for (int i2 = 0; i2 < 4; ++i2) {
            const int idx = base + ((j2 << cqb) + a) * CqX4 + (i2 << cqb) + t;
            xre[j2][i2] = in_re[idx];
            xim[j2][i2] = in_im[idx];
        }

    const int Cq2 = Cq * Cq;
    const int obase = base + a * Cq + t;
    #pragma unroll
    for (int s2 = 0; s2 < 16; ++s2) {
        float accre = 0.f, accim = 0.f;
        #pragma unroll
        for (int i2 = 0; i2 < 4; ++i2)
            #pragma unroll
            for (int j2 = 0; j2 < 4; ++j2) {
                const float mr = m2re_s[(s2 << 4) + (i2 << 2) + j2];
                const float mi = m2im_s[(s2 << 4) + (i2 << 2) + j2];
                const float xr = xre[j2][i2], xi = xim[j2][i2];
                accre += mr * xr - mi * xi;
                accim += mr * xi + mi * xr;
            }
        out_re[obase + s2 * Cq2] = accre;
        out_im[obase + s2 * Cq2] = accim;
    }
}

// ---------------------------------------------------------------------------
// Gather + trace normalization: out[i] = P_re[idx[i]] / trace
// ---------------------------------------------------------------------------
__global__ void gather_idx(const float* __restrict__ Pre, const int* __restrict__ idxs,
                           float* __restrict__ out, const int n)
{
    const int i = blockIdx.x * 256 + threadIdx.x;
    if (i < n) out[i] = Pre[idxs[i]] * g_inv_tr[0];
}

// ---------------------------------------------------------------------------
extern "C" void kernel_launch(void* const* d_in, const int* in_sizes, int n_in,
                              void* d_out, int out_size, void* d_ws, size_t ws_size,
                              hipStream_t stream)
{
    const float* params = (const float*)d_in[0];  // (2, D, RANK) fp32
    const float* Mre    = (const float*)d_in[1];  // (4,2,2)
    const float* Mim    = (const float*)d_in[2];  // (4,2,2)
    const int*   idxs   = (const int*)d_in[3];    // (1M,) indices into [0, 4^12)
    float*       out    = (float*)d_out;

    float* ws   = (float*)d_ws;
    float* Are  = ws;
    float* Aim  = ws + (size_t)NTOT;
    float* Bre  = ws + 2 * (size_t)NTOT;
    float* Bim  = ws + 3 * (size_t)NTOT;

    // rho = U U^H into buffer A
    gemm_rho<<<dim3(64, 64), 256, 0, stream>>>(params, params + (size_t)D * RANK, Are, Aim);
    trace_inv<<<1, 256, 0, stream>>>(Are);
    build_m2<<<1, 256, 0, stream>>>(Mre, Mim);

    // 6 fused 2-qubit passes, ping-pong A <-> B; ends back in A.
    float* ire = Are; float* iim = Aim; float* ore = Bre; float* oim = Bim;
    for (int p = 0; p < 6; ++p) {
        qmt_pass<<<4096, 256, 0, stream>>>(ire, iim, ore, oim, 10 - 2 * p);
        float* tr = ire; ire = ore; ore = tr;
        float* ti = iim; iim = oim; oim = ti;
    }

    gather_idx<<<(out_size + 255) / 256, 256, 0, stream>>>(ire, idxs, out, out_size);
}

// Round 3
// 1004.668 us; speedup vs baseline: 2.4912x; 2.4912x over previous
//
#include <hip/hip_runtime.h>

#define D 4096
#define RANK 1024
#define UELEMS 4194304ULL   // D*RANK
#define NTOT 16777216ULL    // 4^12 = D*D
#define K2 2048             // 2*RANK

typedef __attribute__((ext_vector_type(8))) short bf16x8;
typedef __attribute__((ext_vector_type(4))) float f32x4;

// Small tables live in module __device__ globals, NOT d_ws (d_ws is exactly
// 4 planes = 256 MiB; anything past it faults).
__device__ float g_m2re[256];
__device__ float g_m2im[256];
__device__ float g_inv_tr[1];

__device__ __forceinline__ unsigned short bf16_rne(float x) {
    union { float f; unsigned u; } v; v.f = x;
    unsigned r = v.u + 0x7fffu + ((v.u >> 16) & 1u);
    return (unsigned short)(r >> 16);
}
__device__ __forceinline__ float bf16f(unsigned short h) {
    union { float f; unsigned u; } v; v.u = ((unsigned)h) << 16;
    return v.f;
}

__device__ __forceinline__ void load_lds16(const void* g, void* l) {
    __builtin_amdgcn_global_load_lds(
        (const __attribute__((address_space(1))) unsigned int*)g,
        (__attribute__((address_space(3))) unsigned int*)l, 16, 0, 0);
}

// ---------------------------------------------------------------------------
// Build bf16 hi/lo planes of W = [Ur | Ui] and V = [Ui | -Ur], row-major DxK2.
// rho_re = W W^T, rho_im = V W^T (real embeddings of the complex GEMM).
// ---------------------------------------------------------------------------
__global__ __launch_bounds__(256) void convert_wv(const float* __restrict__ P,
                                                  unsigned short* __restrict__ Wh,
                                                  unsigned short* __restrict__ Wl,
                                                  unsigned short* __restrict__ Vh,
                                                  unsigned short* __restrict__ Vl)
{
    const int tid = blockIdx.x * 256 + threadIdx.x;   // D*RANK/4 threads
    const int d = tid >> 8;
    const int r = (tid & 255) << 2;
    const float4 ur = *(const float4*)&P[(size_t)d * RANK + r];
    const float4 ui = *(const float4*)&P[UELEMS + (size_t)d * RANK + r];
    const float urv[4] = {ur.x, ur.y, ur.z, ur.w};
    const float uiv[4] = {ui.x, ui.y, ui.z, ui.w};

    ushort4 urh, url, uih, uil, nrh, nrl;
    unsigned short* ph;
    #pragma unroll
    for (int e = 0; e < 4; ++e) {
        const unsigned short h1 = bf16_rne(urv[e]);
        const unsigned short l1 = bf16_rne(urv[e] - bf16f(h1));
        const unsigned short h2 = bf16_rne(uiv[e]);
        const unsigned short l2 = bf16_rne(uiv[e] - bf16f(h2));
        ((unsigned short*)&urh)[e] = h1; ((unsigned short*)&url)[e] = l1;
        ((unsigned short*)&uih)[e] = h2; ((unsigned short*)&uil)[e] = l2;
        ((unsigned short*)&nrh)[e] = h1 ^ 0x8000u; ((unsigned short*)&nrl)[e] = l1 ^ 0x8000u;
    }
    const size_t b = (size_t)d * K2 + r;
    *(ushort4*)&Wh[b]        = urh;  *(ushort4*)&Wl[b]        = url;
    *(ushort4*)&Wh[b + RANK] = uih;  *(ushort4*)&Wl[b + RANK] = uil;
    *(ushort4*)&Vh[b]        = uih;  *(ushort4*)&Vl[b]        = uil;
    *(ushort4*)&Vh[b + RANK] = nrh;  *(ushort4*)&Vl[b + RANK] = nrl;
}

// ---------------------------------------------------------------------------
// Split-bf16 bt-GEMM: C[m][n] = sum_k A[m][k]*B[n][k], M=N=4096, K=2048.
// A*B ~= Ah*Bh + Ah*Bl + Al*Bh (fp32 acc).  128x128 tile, BK=32, 4 waves,
// each wave 64x64 = 4x4 mfma_f32_16x16x32_bf16 fragments.
// global_load_lds width-16 staging; LDS 16B-granule XOR swizzle
// (kc ^= (row>>1)&3) makes ds_read_b128 conflict-cheap.
// ---------------------------------------------------------------------------
__global__ __launch_bounds__(256) void gemm_bt_split(const unsigned short* __restrict__ Ah,
                                                     const unsigned short* __restrict__ Al,
                                                     const unsigned short* __restrict__ Bh,
                                                     const unsigned short* __restrict__ Bl,
                                                     float* __restrict__ C)
{
    __shared__ __align__(16) unsigned short sAh[128 * 32];
    __shared__ __align__(16) unsigned short sAl[128 * 32];
    __shared__ __align__(16) unsigned short sBh[128 * 32];
    __shared__ __align__(16) unsigned short sBl[128 * 32];

    const int t = threadIdx.x;
    const int lane = t & 63, w = t >> 6;
    const int wr = w >> 1, wc = w & 1;
    const int row0 = blockIdx.y << 7, col0 = blockIdx.x << 7;

    // staging: granule g = q*256 + t holds (row = g>>2, kc = (g&3) ^ ((row>>1)&3))
    size_t aoff[2], boff[2];
    int ldso[2];
    #pragma unroll
    for (int q = 0; q < 2; ++q) {
        const int g = q * 256 + t;
        const int row = g >> 2;
        const int kc = (g & 3) ^ ((row >> 1) & 3);
        aoff[q] = (size_t)(row0 + row) * K2 + kc * 8;
        boff[q] = (size_t)(col0 + row) * K2 + kc * 8;
        ldso[q] = (q * 256 + w * 64) * 8;  // wave-uniform granule base (ushorts)
    }

    const int m = lane & 15, gq = lane >> 4;
    const int swz = (m >> 1) & 3;
    const int fko = (gq ^ swz) * 8;  // fragment k-chunk offset in ushorts

    f32x4 acc[4][4];
    #pragma unroll
    for (int i = 0; i < 4; ++i)
        #pragma unroll
        for (int j = 0; j < 4; ++j)
            acc[i][j] = (f32x4){0.f, 0.f, 0.f, 0.f};

    for (int kt = 0; kt < K2; kt += 32) {
        #pragma unroll
        for (int q = 0; q < 2; ++q) {
            load_lds16(Ah + aoff[q] + kt, &sAh[ldso[q]]);
            load_lds16(Al + aoff[q] + kt, &sAl[ldso[q]]);
            load_lds16(Bh + boff[q] + kt, &sBh[ldso[q]]);
            load_lds16(Bl + boff[q] + kt, &sBl[ldso[q]]);
        }
        __syncthreads();

        bf16x8 fah[4], fal[4], fbh[4], fbl[4];
        #pragma unroll
        for (int i = 0; i < 4; ++i) {
            const int off = (wr * 64 + i * 16 + m) * 32 + fko;
            fah[i] = *(const bf16x8*)&sAh[off];
            fal[i] = *(const bf16x8*)&sAl[off];
        }
        #pragma unroll
        for (int j = 0; j < 4; ++j) {
            const int off = (wc * 64 + j * 16 + m) * 32 + fko;
            fbh[j] = *(const bf16x8*)&sBh[off];
            fbl[j] = *(const bf16x8*)&sBl[off];
        }
        #pragma unroll
        for (int i = 0; i < 4; ++i)
            #pragma unroll
            for (int j = 0; j < 4; ++j) {
                acc[i][j] = __builtin_amdgcn_mfma_f32_16x16x32_bf16(fah[i], fbh[j], acc[i][j], 0, 0, 0);
                acc[i][j] = __builtin_amdgcn_mfma_f32_16x16x32_bf16(fah[i], fbl[j], acc[i][j], 0, 0, 0);
                acc[i][j] = __builtin_amdgcn_mfma_f32_16x16x32_bf16(fal[i], fbh[j], acc[i][j], 0, 0, 0);
            }
        __syncthreads();
    }

    // C/D layout: col = lane&15, row = (lane>>4)*4 + reg
    #pragma unroll
    for (int i = 0; i < 4; ++i)
        #pragma unroll
        for (int j = 0; j < 4; ++j) {
            const int col = col0 + wc * 64 + j * 16 + m;
            #pragma unroll
            for (int r = 0; r < 4; ++r) {
                const int row = row0 + wr * 64 + i * 16 + gq * 4 + r;
                C[(size_t)row * D + col] = acc[i][j][r];
            }
        }
}

// ---------------------------------------------------------------------------
__global__ void trace_inv(const float* __restrict__ rho_re)
{
    __shared__ float red[256];
    float s = 0.f;
    for (int d = threadIdx.x; d < D; d += 256)
        s += rho_re[(size_t)d * (D + 1)];
    red[threadIdx.x] = s;
    __syncthreads();
    for (int off = 128; off > 0; off >>= 1) {
        if (threadIdx.x < off) red[threadIdx.x] += red[threadIdx.x + off];
        __syncthreads();
    }
    if (threadIdx.x == 0) g_inv_tr[0] = 1.0f / red[0];
}

// ---------------------------------------------------------------------------
__global__ void build_m2(const float* __restrict__ Mre, const float* __restrict__ Mim)
{
    const int tid = threadIdx.x;  // s2*16 + i2*4 + j2
    const int s2 = tid >> 4, t2 = tid & 15;
    const int i2 = t2 >> 2, j2 = t2 & 3;
    const int sa = s2 >> 2, sb = s2 & 3;
    const int ia = i2 >> 1, ib = i2 & 1;
    const int ja = j2 >> 1, jb = j2 & 1;
    const float ar = Mre[sa * 4 + ia * 2 + ja], ai = Mim[sa * 4 + ia * 2 + ja];
    const float br = Mre[sb * 4 + ib * 2 + jb], bi = Mim[sb * 4 + ib * 2 + jb];
    g_m2re[tid] = ar * br - ai * bi;
    g_m2im[tid] = ar * bi + ai * br;
}

// ---------------------------------------------------------------------------
__global__ __launch_bounds__(256) void qmt_pass(const float* __restrict__ in_re,
                                                const float* __restrict__ in_im,
                                                float* __restrict__ out_re,
                                                float* __restrict__ out_im,
                                                const int cqb)
{
    __shared__ float m2re_s[256], m2im_s[256];
    m2re_s[threadIdx.x] = g_m2re[threadIdx.x];
    m2im_s[threadIdx.x] = g_m2im[threadIdx.x];
    __syncthreads();

    const int tid = blockIdx.x * 256 + threadIdx.x;
    const int Cq = 1 << cqb;
    const int t = tid & (Cq - 1);
    const int a = (tid >> cqb) & (Cq - 1);
    const int k = tid >> (2 * cqb);
    const int base = k << (4 + 2 * cqb);
    const int CqX4 = Cq << 2;

    float xre[4][4], xim[4][4];
    #pragma unroll
    for (int j2 = 0; j2 < 4; ++j2)
        #pragma unroll
        for (int i2 = 0; i2 < 4; ++i2) {
            const int idx = base + ((j2 << cqb) + a) * CqX4 + (i2 << cqb) + t;
            xre[j2][i2] = in_re[idx];
            xim[j2][i2] = in_im[idx];
        }

    const int Cq2 = Cq * Cq;
    const int obase = base + a * Cq + t;
    #pragma unroll
    for (int s2 = 0; s2 < 16; ++s2) {
        float accre = 0.f, accim = 0.f;
        #pragma unroll
        for (int i2 = 0; i2 < 4; ++i2)
            #pragma unroll
            for (int j2 = 0; j2 < 4; ++j2) {
                const float mr = m2re_s[(s2 << 4) + (i2 << 2) + j2];
                const float mi = m2im_s[(s2 << 4) + (i2 << 2) + j2];
                const float xr = xre[j2][i2], xi = xim[j2][i2];
                accre += mr * xr - mi * xi;
                accim += mr * xi + mi * xr;
            }
        out_re[obase + s2 * Cq2] = accre;
        out_im[obase + s2 * Cq2] = accim;
    }
}

// ---------------------------------------------------------------------------
__global__ void gather_idx(const float* __restrict__ Pre, const int* __restrict__ idxs,
                           float* __restrict__ out, const int n)
{
    const int i = blockIdx.x * 256 + threadIdx.x;
    if (i < n) out[i] = Pre[idxs[i]] * g_inv_tr[0];
}

// ---------------------------------------------------------------------------
extern "C" void kernel_launch(void* const* d_in, const int* in_sizes, int n_in,
                              void* d_out, int out_size, void* d_ws, size_t ws_size,
                              hipStream_t stream)
{
    const float* params = (const float*)d_in[0];  // (2, D, RANK) fp32
    const float* Mre    = (const float*)d_in[1];
    const float* Mim    = (const float*)d_in[2];
    const int*   idxs   = (const int*)d_in[3];
    float*       out    = (float*)d_out;

    float* ws  = (float*)d_ws;
    float* Are = ws;
    float* Aim = ws + NTOT;
    float* Bre = ws + 2 * NTOT;
    float* Bim = ws + 3 * NTOT;

    // bf16 hi/lo planes of W,V live in the (currently dead) B region:
    // 4 planes x 16 MB = 64 MB <= 128 MB. Dead after gemm; pass 0 overwrites.
    unsigned short* Wh = (unsigned short*)(ws + 2 * NTOT);
    unsigned short* Wl = Wh + 2 * UELEMS;
    unsigned short* Vh = Wl + 2 * UELEMS;
    unsigned short* Vl = Vh + 2 * UELEMS;

    convert_wv<<<4096, 256, 0, stream>>>(params, Wh, Wl, Vh, Vl);
    gemm_bt_split<<<dim3(32, 32), 256, 0, stream>>>(Wh, Wl, Wh, Wl, Are);  // rho_re
    gemm_bt_split<<<dim3(32, 32), 256, 0, stream>>>(Vh, Vl, Wh, Wl, Aim);  // rho_im
    trace_inv<<<1, 256, 0, stream>>>(Are);
    build_m2<<<1, 256, 0, stream>>>(Mre, Mim);

    // 6 fused 2-qubit passes, ping-pong A <-> B; ends back in A.
    float* ire = Are; float* iim = Aim; float* ore = Bre; float* oim = Bim;
    for (int p = 0; p < 6; ++p) {
        qmt_pass<<<4096, 256, 0, stream>>>(ire, iim, ore, oim, 10 - 2 * p);
        float* tr = ire; ire = ore; ore = tr;
        float* ti = iim; iim = oim; oim = ti;
    }

    gather_idx<<<(out_size + 255) / 256, 256, 0, stream>>>(ire, idxs, out, out_size);
}

// Round 4
// 852.005 us; speedup vs baseline: 2.9375x; 1.1792x over previous
//
#include <hip/hip_runtime.h>

#define D 4096
#define RANK 1024
#define K2 2048
#define UELEMS 4194304ULL   // D*RANK
#define NTOT 16777216ULL    // 4^12 = D*D

typedef __attribute__((ext_vector_type(8))) short bf16x8;
typedef __attribute__((ext_vector_type(4))) float f32x4;

__device__ float g_inv_tr[1];

static __device__ __forceinline__ unsigned short bf16_rne(float x) {
    union { float f; unsigned u; } v; v.f = x;
    unsigned r = v.u + 0x7fffu + ((v.u >> 16) & 1u);
    return (unsigned short)(r >> 16);
}
static __device__ __forceinline__ float bf16f(unsigned short h) {
    union { float f; unsigned u; } v; v.u = ((unsigned)h) << 16;
    return v.f;
}
static __device__ __forceinline__ void load_lds16(const void* g, void* l) {
    __builtin_amdgcn_global_load_lds(
        (const __attribute__((address_space(1))) unsigned int*)g,
        (__attribute__((address_space(3))) unsigned int*)l, 16, 0, 0);
}
static __device__ __forceinline__ bf16x8 negbf(bf16x8 v) {
    union { bf16x8 b; uint4 u; } w; w.b = v;
    w.u.x ^= 0x80008000u; w.u.y ^= 0x80008000u;
    w.u.z ^= 0x80008000u; w.u.w ^= 0x80008000u;
    return w.b;
}

// ---------------------------------------------------------------------------
// bf16 hi/lo split planes of W = [Ur | Ui], row-major D x K2.
// rho_re = W W^T; rho_im = W2 W1^T - W1 W2^T (halves of W).
// ---------------------------------------------------------------------------
__global__ __launch_bounds__(256) void convert_w(const float* __restrict__ P,
                                                 unsigned short* __restrict__ Wh,
                                                 unsigned short* __restrict__ Wl)
{
    const int tid = blockIdx.x * 256 + threadIdx.x;   // D*RANK/4 threads
    const int d = tid >> 8;
    const int r = (tid & 255) << 2;
    const float4 ur = *(const float4*)&P[(size_t)d * RANK + r];
    const float4 ui = *(const float4*)&P[UELEMS + (size_t)d * RANK + r];
    const float urv[4] = {ur.x, ur.y, ur.z, ur.w};
    const float uiv[4] = {ui.x, ui.y, ui.z, ui.w};

    ushort4 h1, l1, h2, l2;
    #pragma unroll
    for (int e = 0; e < 4; ++e) {
        const unsigned short a = bf16_rne(urv[e]);
        ((unsigned short*)&h1)[e] = a;
        ((unsigned short*)&l1)[e] = bf16_rne(urv[e] - bf16f(a));
        const unsigned short b = bf16_rne(uiv[e]);
        ((unsigned short*)&h2)[e] = b;
        ((unsigned short*)&l2)[e] = bf16_rne(uiv[e] - bf16f(b));
    }
    const size_t bidx = (size_t)d * K2 + r;
    *(ushort4*)&Wh[bidx]        = h1;  *(ushort4*)&Wl[bidx]        = l1;
    *(ushort4*)&Wh[bidx + RANK] = h2;  *(ushort4*)&Wl[bidx + RANK] = l2;
}

// ---------------------------------------------------------------------------
// Fused Hermitian GEMM: lower-triangle 64x128 tiles of rho (interleaved
// float2 {re,im}), mirror written as conjugate. Split-bf16 (3-term) MFMA.
// Per k-step stages A,B chunks at both kt and kt+1024:
//   re += A1*B1 + A2*B2 ;  im += A2*B1 + (-A1)*B2
// ---------------------------------------------------------------------------
__global__ __launch_bounds__(256) void gemm_rho_fused(const unsigned short* __restrict__ Wh,
                                                      const unsigned short* __restrict__ Wl,
                                                      float2* __restrict__ rho)
{
    __shared__ __align__(16) unsigned short sA1h[64 * 32];
    __shared__ __align__(16) unsigned short sA1l[64 * 32];
    __shared__ __align__(16) unsigned short sA2h[64 * 32];
    __shared__ __align__(16) unsigned short sA2l[64 * 32];
    __shared__ __align__(16) unsigned short sB1h[128 * 32];
    __shared__ __align__(16) unsigned short sB1l[128 * 32];
    __shared__ __align__(16) unsigned short sB2h[128 * 32];
    __shared__ __align__(16) unsigned short sB2l[128 * 32];

    // triangle mapping: blocks per bj = 64-2*bj, offset(bj) = bj*(65-bj)
    const int b = blockIdx.x;
    int bj = (int)((65.0f - sqrtf(4225.0f - 4.0f * (float)b)) * 0.5f);
    while (bj > 0 && bj * (65 - bj) > b) --bj;
    while ((bj + 1) * (64 - bj) <= b) ++bj;
    const int bi = 2 * bj + (b - bj * (65 - bj));
    const int row0 = bi << 6, col0 = bj << 7;
    const bool full = (bi >= 2 * bj + 2);   // fully below diagonal

    const int t = threadIdx.x;
    const int lane = t & 63, w = t >> 6;
    const int wr = w >> 1, wc = w & 1;

    // staging coords (16B granules, XOR-swizzled k-chunks)
    const int rowA = t >> 2;
    const int kcA = (t & 3) ^ ((rowA >> 1) & 3);
    const size_t aoff = (size_t)(row0 + rowA) * K2 + kcA * 8;
    const int ldsA = t * 8;
    size_t boff[2]; int ldsB[2];
    #pragma unroll
    for (int q = 0; q < 2; ++q) {
        const int g = q * 256 + t;
        const int rowB = g >> 2;
        const int kcB = (g & 3) ^ ((rowB >> 1) & 3);
        boff[q] = (size_t)(col0 + rowB) * K2 + kcB * 8;
        ldsB[q] = g * 8;
    }

    const int m = lane & 15, gq = lane >> 4;
    const int fko = (gq ^ ((m >> 1) & 3)) * 8;

    f32x4 accre[2][4], accim[2][4];
    #pragma unroll
    for (int i = 0; i < 2; ++i)
        #pragma unroll
        for (int j = 0; j < 4; ++j) {
            accre[i][j] = (f32x4){0.f, 0.f, 0.f, 0.f};
            accim[i][j] = (f32x4){0.f, 0.f, 0.f, 0.f};
        }

    for (int kt = 0; kt < RANK; kt += 32) {
        load_lds16(Wh + aoff + kt,        &sA1h[ldsA]);
        load_lds16(Wl + aoff + kt,        &sA1l[ldsA]);
        load_lds16(Wh + aoff + kt + RANK, &sA2h[ldsA]);
        load_lds16(Wl + aoff + kt + RANK, &sA2l[ldsA]);
        #pragma unroll
        for (int q = 0; q < 2; ++q) {
            load_lds16(Wh + boff[q] + kt,        &sB1h[ldsB[q]]);
            load_lds16(Wl + boff[q] + kt,        &sB1l[ldsB[q]]);
            load_lds16(Wh + boff[q] + kt + RANK, &sB2h[ldsB[q]]);
            load_lds16(Wl + boff[q] + kt + RANK, &sB2l[ldsB[q]]);
        }
        __syncthreads();

        bf16x8 fa1h[2], fa1l[2], fa2h[2], fa2l[2], na1h[2], na1l[2];
        #pragma unroll
        for (int i = 0; i < 2; ++i) {
            const int off = (wr * 32 + i * 16 + m) * 32 + fko;
            fa1h[i] = *(const bf16x8*)&sA1h[off];
            fa1l[i] = *(const bf16x8*)&sA1l[off];
            fa2h[i] = *(const bf16x8*)&sA2h[off];
            fa2l[i] = *(const bf16x8*)&sA2l[off];
            na1h[i] = negbf(fa1h[i]);
            na1l[i] = negbf(fa1l[i]);
        }
        bf16x8 fb1h[4], fb1l[4], fb2h[4], fb2l[4];
        #pragma unroll
        for (int j = 0; j < 4; ++j) {
            const int off = (wc * 64 + j * 16 + m) * 32 + fko;
            fb1h[j] = *(const bf16x8*)&sB1h[off];
            fb1l[j] = *(const bf16x8*)&sB1l[off];
            fb2h[j] = *(const bf16x8*)&sB2h[off];
            fb2l[j] = *(const bf16x8*)&sB2l[off];
        }
        #pragma unroll
        for (int i = 0; i < 2; ++i)
            #pragma unroll
            for (int j = 0; j < 4; ++j) {
                f32x4 r = accre[i][j];
                r = __builtin_amdgcn_mfma_f32_16x16x32_bf16(fa1h[i], fb1h[j], r, 0, 0, 0);
                r = __builtin_amdgcn_mfma_f32_16x16x32_bf16(fa1h[i], fb1l[j], r, 0, 0, 0);
                r = __builtin_amdgcn_mfma_f32_16x16x32_bf16(fa1l[i], fb1h[j], r, 0, 0, 0);
                r = __builtin_amdgcn_mfma_f32_16x16x32_bf16(fa2h[i], fb2h[j], r, 0, 0, 0);
                r = __builtin_amdgcn_mfma_f32_16x16x32_bf16(fa2h[i], fb2l[j], r, 0, 0, 0);
                r = __builtin_amdgcn_mfma_f32_16x16x32_bf16(fa2l[i], fb2h[j], r, 0, 0, 0);
                accre[i][j] = r;
                f32x4 s = accim[i][j];
                s = __builtin_amdgcn_mfma_f32_16x16x32_bf16(fa2h[i], fb1h[j], s, 0, 0, 0);
                s = __builtin_amdgcn_mfma_f32_16x16x32_bf16(fa2h[i], fb1l[j], s, 0, 0, 0);
                s = __builtin_amdgcn_mfma_f32_16x16x32_bf16(fa2l[i], fb1h[j], s, 0, 0, 0);
                s = __builtin_amdgcn_mfma_f32_16x16x32_bf16(na1h[i], fb2h[j], s, 0, 0, 0);
                s = __builtin_amdgcn_mfma_f32_16x16x32_bf16(na1h[i], fb2l[j], s, 0, 0, 0);
                s = __builtin_amdgcn_mfma_f32_16x16x32_bf16(na1l[i], fb2h[j], s, 0, 0, 0);
                accim[i][j] = s;
            }
        __syncthreads();
    }

    // C/D layout: col = lane&15, row = (lane>>4)*4 + reg
    #pragma unroll
    for (int i = 0; i < 2; ++i)
        #pragma unroll
        for (int j = 0; j < 4; ++j) {
            const int col = col0 + wc * 64 + j * 16 + m;
            #pragma unroll
            for (int r = 0; r < 4; ++r) {
                const int row = row0 + wr * 32 + i * 16 + gq * 4 + r;
                const float re = accre[i][j][r], im = accim[i][j][r];
                if (full || row >= col) rho[(size_t)row * D + col] = make_float2(re, im);
                if (full || row > col)  rho[(size_t)col * D + row] = make_float2(re, -im);
            }
        }
}

// ---------------------------------------------------------------------------
__global__ void trace_inv(const float2* __restrict__ rho)
{
    __shared__ float red[256];
    float s = 0.f;
    for (int d = threadIdx.x; d < D; d += 256)
        s += rho[(size_t)d * (D + 1)].x;
    red[threadIdx.x] = s;
    __syncthreads();
    for (int off = 128; off > 0; off >>= 1) {
        if (threadIdx.x < off) red[threadIdx.x] += red[threadIdx.x + off];
        __syncthreads();
    }
    if (threadIdx.x == 0) g_inv_tr[0] = 1.0f / red[0];
}

// ---------------------------------------------------------------------------
// Fused 3-qubit pass, staged in-register contraction (768 cmul/thread).
// in  [k, 8(j3), R, 8(i3), C] complex-interleaved; out [k*64+s3, R, C].
// s3 = sa*16+sb*4+sc, with qubit-a = top row/col bit. M[s][i][j]: j pairs
// with row bit, i with col bit (einsum 'sij,kjait->ksat'). M reads are
// wave-uniform scalar loads.
// ---------------------------------------------------------------------------
__global__ __launch_bounds__(256) void qmt3(const float2* __restrict__ in,
                                            float2* __restrict__ out,
                                            const float* __restrict__ Mre,
                                            const float* __restrict__ Mim,
                                            const int cqb)
{
    const int tid = blockIdx.x * 256 + threadIdx.x;   // NTOT/64 threads
    const int C = 1 << cqb;
    const int t = tid & (C - 1);
    const int a = (tid >> cqb) & (C - 1);
    const int k = tid >> (2 * cqb);
    const size_t base = (size_t)k << (6 + 2 * cqb);
    const size_t roff = base + ((size_t)a << (3 + cqb)) + t;

    float2 x[64];
    #pragma unroll
    for (int j3 = 0; j3 < 8; ++j3)
        #pragma unroll
        for (int i3 = 0; i3 < 8; ++i3)
            x[j3 * 8 + i3] = in[roff + ((size_t)j3 << (3 + 2 * cqb)) + ((size_t)i3 << cqb)];

    // stage c: contract (jc, ic) -> buf[jj][sc][ii]  (jj=(ja jb), ii=(ia ib))
    #pragma unroll
    for (int jj = 0; jj < 4; ++jj) {
        float2 y[16];
        #pragma unroll
        for (int sc = 0; sc < 4; ++sc)
            #pragma unroll
            for (int ii = 0; ii < 4; ++ii) {
                float2 acc = make_float2(0.f, 0.f);
                #pragma unroll
                for (int ic = 0; ic < 2; ++ic)
                    #pragma unroll
                    for (int jc = 0; jc < 2; ++jc) {
                        const float mr = Mre[sc * 4 + ic * 2 + jc];
                        const float mi = Mim[sc * 4 + ic * 2 + jc];
                        const float2 v = x[jj * 16 + jc * 8 + ii * 2 + ic];
                        acc.x += mr * v.x - mi * v.y;
                        acc.y += mr * v.y + mi * v.x;
                    }
                y[sc * 4 + ii] = acc;
            }
        #pragma unroll
        for (int q = 0; q < 16; ++q) x[jj * 16 + q] = y[q];
    }

    // stage b: contract (jb, ib) -> buf[ja][sbH][sc][ia][sbL]
    #pragma unroll
    for (int ja = 0; ja < 2; ++ja)
        #pragma unroll
        for (int sc = 0; sc < 4; ++sc) {
            float2 z[8];
            #pragma unroll
            for (int sb = 0; sb < 4; ++sb)
                #pragma unroll
                for (int ia = 0; ia < 2; ++ia) {
                    float2 acc = make_float2(0.f, 0.f);
                    #pragma unroll
                    for (int ib = 0; ib < 2; ++ib)
                        #pragma unroll
                        for (int jb = 0; jb < 2; ++jb) {
                            const float mr = Mre[sb * 4 + ib * 2 + jb];
                            const float mi = Mim[sb * 4 + ib * 2 + jb];
                            const float2 v = x[(ja * 2 + jb) * 16 + sc * 4 + ia * 2 + ib];
                            acc.x += mr * v.x - mi * v.y;
                            acc.y += mr * v.y + mi * v.x;
                        }
                    z[sb * 2 + ia] = acc;
                }
            #pragma unroll
            for (int sb = 0; sb < 4; ++sb)
                #pragma unroll
                for (int ia = 0; ia < 2; ++ia)
                    x[ja * 32 + (sb >> 1) * 16 + sc * 4 + ia * 2 + (sb & 1)] = z[sb * 2 + ia];
        }

    // stage a: contract (ja, ia), write out
    const size_t woff = base + ((size_t)a << cqb) + t;
    #pragma unroll
    for (int sbH = 0; sbH < 2; ++sbH)
        #pragma unroll
        for (int sc = 0; sc < 4; ++sc)
            #pragma unroll
            for (int sbL = 0; sbL < 2; ++sbL) {
                const int sb = sbH * 2 + sbL;
                #pragma unroll
                for (int sa = 0; sa < 4; ++sa) {
                    float2 acc = make_float2(0.f, 0.f);
                    #pragma unroll
                    for (int ia = 0; ia < 2; ++ia)
                        #pragma unroll
                        for (int ja = 0; ja < 2; ++ja) {
                            const float mr = Mre[sa * 4 + ia * 2 + ja];
                            const float mi = Mim[sa * 4 + ia * 2 + ja];
                            const float2 v = x[ja * 32 + sbH * 16 + sc * 4 + ia * 2 + sbL];
                            acc.x += mr * v.x - mi * v.y;
                            acc.y += mr * v.y + mi * v.x;
                        }
                    const int s3 = sa * 16 + sb * 4 + sc;
                    out[woff + ((size_t)s3 << (2 * cqb))] = acc;
                }
            }
}

// ---------------------------------------------------------------------------
__global__ void gather_idx(const float2* __restrict__ P, const int* __restrict__ idxs,
                           float* __restrict__ out, const int n)
{
    const int i = blockIdx.x * 256 + threadIdx.x;
    if (i < n) out[i] = P[idxs[i]].x * g_inv_tr[0];
}

// ---------------------------------------------------------------------------
extern "C" void kernel_launch(void* const* d_in, const int* in_sizes, int n_in,
                              void* d_out, int out_size, void* d_ws, size_t ws_size,
                              hipStream_t stream)
{
    const float* params = (const float*)d_in[0];  // (2, D, RANK) fp32
    const float* Mre    = (const float*)d_in[1];
    const float* Mim    = (const float*)d_in[2];
    const int*   idxs   = (const int*)d_in[3];
    float*       out    = (float*)d_out;

    float* ws = (float*)d_ws;
    float2* A  = (float2*)ws;                 // 134 MB interleaved plane
    float2* Bp = (float2*)(ws + 2 * NTOT);    // 134 MB interleaved plane
    // bf16 W planes live inside the (dead until pass 0) B region: 2 x 16.8 MB
    unsigned short* Wh = (unsigned short*)Bp;
    unsigned short* Wl = Wh + 2 * UELEMS;

    convert_w<<<4096, 256, 0, stream>>>(params, Wh, Wl);
    gemm_rho_fused<<<1056, 256, 0, stream>>>(Wh, Wl, A);
    trace_inv<<<1, 256, 0, stream>>>(A);

    qmt3<<<1024, 256, 0, stream>>>(A,  Bp, Mre, Mim, 9);
    qmt3<<<1024, 256, 0, stream>>>(Bp, A,  Mre, Mim, 6);
    qmt3<<<1024, 256, 0, stream>>>(A,  Bp, Mre, Mim, 3);
    qmt3<<<1024, 256, 0, stream>>>(Bp, A,  Mre, Mim, 0);

    gather_idx<<<(out_size + 255) / 256, 256, 0, stream>>>(A, idxs, out, out_size);
}

// Round 5
// 613.670 us; speedup vs baseline: 4.0784x; 1.3884x over previous
//
#include <hip/hip_runtime.h>

#define D 4096
#define RANK 1024
#define K2 2048
#define UELEMS 4194304ULL   // D*RANK
#define NTOT 16777216ULL    // 4^12 = D*D

typedef __attribute__((ext_vector_type(8))) short bf16x8;
typedef __attribute__((ext_vector_type(4))) float f32x4;

__device__ float g_inv_tr[1];

static __device__ __forceinline__ unsigned short bf16_rne(float x) {
    union { float f; unsigned u; } v; v.f = x;
    unsigned r = v.u + 0x7fffu + ((v.u >> 16) & 1u);
    return (unsigned short)(r >> 16);
}
static __device__ __forceinline__ float bf16f(unsigned short h) {
    union { float f; unsigned u; } v; v.u = ((unsigned)h) << 16;
    return v.f;
}
static __device__ __forceinline__ void load_lds16(const void* g, void* l) {
    __builtin_amdgcn_global_load_lds(
        (const __attribute__((address_space(1))) unsigned int*)g,
        (__attribute__((address_space(3))) unsigned int*)l, 16, 0, 0);
}
static __device__ __forceinline__ bf16x8 negbf(bf16x8 v) {
    union { bf16x8 b; uint4 u; } w; w.b = v;
    w.u.x ^= 0x80008000u; w.u.y ^= 0x80008000u;
    w.u.z ^= 0x80008000u; w.u.w ^= 0x80008000u;
    return w.b;
}

// ---------------------------------------------------------------------------
// bf16 hi/lo split planes of W = [Ur | Ui], row-major D x K2.
// ---------------------------------------------------------------------------
__global__ __launch_bounds__(256) void convert_w(const float* __restrict__ P,
                                                 unsigned short* __restrict__ Wh,
                                                 unsigned short* __restrict__ Wl)
{
    const int tid = blockIdx.x * 256 + threadIdx.x;   // D*RANK/4 threads
    const int d = tid >> 8;
    const int r = (tid & 255) << 2;
    const float4 ur = *(const float4*)&P[(size_t)d * RANK + r];
    const float4 ui = *(const float4*)&P[UELEMS + (size_t)d * RANK + r];
    const float urv[4] = {ur.x, ur.y, ur.z, ur.w};
    const float uiv[4] = {ui.x, ui.y, ui.z, ui.w};

    ushort4 h1, l1, h2, l2;
    #pragma unroll
    for (int e = 0; e < 4; ++e) {
        const unsigned short a = bf16_rne(urv[e]);
        ((unsigned short*)&h1)[e] = a;
        ((unsigned short*)&l1)[e] = bf16_rne(urv[e] - bf16f(a));
        const unsigned short b = bf16_rne(uiv[e]);
        ((unsigned short*)&h2)[e] = b;
        ((unsigned short*)&l2)[e] = bf16_rne(uiv[e] - bf16f(b));
    }
    const size_t bidx = (size_t)d * K2 + r;
    *(ushort4*)&Wh[bidx]        = h1;  *(ushort4*)&Wl[bidx]        = l1;
    *(ushort4*)&Wh[bidx + RANK] = h2;  *(ushort4*)&Wl[bidx + RANK] = l2;
}

// ---------------------------------------------------------------------------
// Fused Hermitian GEMM (unchanged from round 4): lower-triangle 64x128 tiles
// of rho (interleaved float2), mirror written as conjugate.
// ---------------------------------------------------------------------------
__global__ __launch_bounds__(256) void gemm_rho_fused(const unsigned short* __restrict__ Wh,
                                                      const unsigned short* __restrict__ Wl,
                                                      float2* __restrict__ rho)
{
    __shared__ __align__(16) unsigned short sA1h[64 * 32];
    __shared__ __align__(16) unsigned short sA1l[64 * 32];
    __shared__ __align__(16) unsigned short sA2h[64 * 32];
    __shared__ __align__(16) unsigned short sA2l[64 * 32];
    __shared__ __align__(16) unsigned short sB1h[128 * 32];
    __shared__ __align__(16) unsigned short sB1l[128 * 32];
    __shared__ __align__(16) unsigned short sB2h[128 * 32];
    __shared__ __align__(16) unsigned short sB2l[128 * 32];

    const int b = blockIdx.x;
    int bj = (int)((65.0f - sqrtf(4225.0f - 4.0f * (float)b)) * 0.5f);
    while (bj > 0 && bj * (65 - bj) > b) --bj;
    while ((bj + 1) * (64 - bj) <= b) ++bj;
    const int bi = 2 * bj + (b - bj * (65 - bj));
    const int row0 = bi << 6, col0 = bj << 7;
    const bool full = (bi >= 2 * bj + 2);

    const int t = threadIdx.x;
    const int lane = t & 63, w = t >> 6;
    const int wr = w >> 1, wc = w & 1;

    const int rowA = t >> 2;
    const int kcA = (t & 3) ^ ((rowA >> 1) & 3);
    const size_t aoff = (size_t)(row0 + rowA) * K2 + kcA * 8;
    const int ldsA = t * 8;
    size_t boff[2]; int ldsB[2];
    #pragma unroll
    for (int q = 0; q < 2; ++q) {
        const int g = q * 256 + t;
        const int rowB = g >> 2;
        const int kcB = (g & 3) ^ ((rowB >> 1) & 3);
        boff[q] = (size_t)(col0 + rowB) * K2 + kcB * 8;
        ldsB[q] = g * 8;
    }

    const int m = lane & 15, gq = lane >> 4;
    const int fko = (gq ^ ((m >> 1) & 3)) * 8;

    f32x4 accre[2][4], accim[2][4];
    #pragma unroll
    for (int i = 0; i < 2; ++i)
        #pragma unroll
        for (int j = 0; j < 4; ++j) {
            accre[i][j] = (f32x4){0.f, 0.f, 0.f, 0.f};
            accim[i][j] = (f32x4){0.f, 0.f, 0.f, 0.f};
        }

    for (int kt = 0; kt < RANK; kt += 32) {
        load_lds16(Wh + aoff + kt,        &sA1h[ldsA]);
        load_lds16(Wl + aoff + kt,        &sA1l[ldsA]);
        load_lds16(Wh + aoff + kt + RANK, &sA2h[ldsA]);
        load_lds16(Wl + aoff + kt + RANK, &sA2l[ldsA]);
        #pragma unroll
        for (int q = 0; q < 2; ++q) {
            load_lds16(Wh + boff[q] + kt,        &sB1h[ldsB[q]]);
            load_lds16(Wl + boff[q] + kt,        &sB1l[ldsB[q]]);
            load_lds16(Wh + boff[q] + kt + RANK, &sB2h[ldsB[q]]);
            load_lds16(Wl + boff[q] + kt + RANK, &sB2l[ldsB[q]]);
        }
        __syncthreads();

        bf16x8 fa1h[2], fa1l[2], fa2h[2], fa2l[2], na1h[2], na1l[2];
        #pragma unroll
        for (int i = 0; i < 2; ++i) {
            const int off = (wr * 32 + i * 16 + m) * 32 + fko;
            fa1h[i] = *(const bf16x8*)&sA1h[off];
            fa1l[i] = *(const bf16x8*)&sA1l[off];
            fa2h[i] = *(const bf16x8*)&sA2h[off];
            fa2l[i] = *(const bf16x8*)&sA2l[off];
            na1h[i] = negbf(fa1h[i]);
            na1l[i] = negbf(fa1l[i]);
        }
        bf16x8 fb1h[4], fb1l[4], fb2h[4], fb2l[4];
        #pragma unroll
        for (int j = 0; j < 4; ++j) {
            const int off = (wc * 64 + j * 16 + m) * 32 + fko;
            fb1h[j] = *(const bf16x8*)&sB1h[off];
            fb1l[j] = *(const bf16x8*)&sB1l[off];
            fb2h[j] = *(const bf16x8*)&sB2h[off];
            fb2l[j] = *(const bf16x8*)&sB2l[off];
        }
        #pragma unroll
        for (int i = 0; i < 2; ++i)
            #pragma unroll
            for (int j = 0; j < 4; ++j) {
                f32x4 r = accre[i][j];
                r = __builtin_amdgcn_mfma_f32_16x16x32_bf16(fa1h[i], fb1h[j], r, 0, 0, 0);
                r = __builtin_amdgcn_mfma_f32_16x16x32_bf16(fa1h[i], fb1l[j], r, 0, 0, 0);
                r = __builtin_amdgcn_mfma_f32_16x16x32_bf16(fa1l[i], fb1h[j], r, 0, 0, 0);
                r = __builtin_amdgcn_mfma_f32_16x16x32_bf16(fa2h[i], fb2h[j], r, 0, 0, 0);
                r = __builtin_amdgcn_mfma_f32_16x16x32_bf16(fa2h[i], fb2l[j], r, 0, 0, 0);
                r = __builtin_amdgcn_mfma_f32_16x16x32_bf16(fa2l[i], fb2h[j], r, 0, 0, 0);
                accre[i][j] = r;
                f32x4 s = accim[i][j];
                s = __builtin_amdgcn_mfma_f32_16x16x32_bf16(fa2h[i], fb1h[j], s, 0, 0, 0);
                s = __builtin_amdgcn_mfma_f32_16x16x32_bf16(fa2h[i], fb1l[j], s, 0, 0, 0);
                s = __builtin_amdgcn_mfma_f32_16x16x32_bf16(fa2l[i], fb1h[j], s, 0, 0, 0);
                s = __builtin_amdgcn_mfma_f32_16x16x32_bf16(na1h[i], fb2h[j], s, 0, 0, 0);
                s = __builtin_amdgcn_mfma_f32_16x16x32_bf16(na1h[i], fb2l[j], s, 0, 0, 0);
                s = __builtin_amdgcn_mfma_f32_16x16x32_bf16(na1l[i], fb2h[j], s, 0, 0, 0);
                accim[i][j] = s;
            }
        __syncthreads();
    }

    #pragma unroll
    for (int i = 0; i < 2; ++i)
        #pragma unroll
        for (int j = 0; j < 4; ++j) {
            const int col = col0 + wc * 64 + j * 16 + m;
            #pragma unroll
            for (int r = 0; r < 4; ++r) {
                const int row = row0 + wr * 32 + i * 16 + gq * 4 + r;
                const float re = accre[i][j][r], im = accim[i][j][r];
                if (full || row >= col) rho[(size_t)row * D + col] = make_float2(re, im);
                if (full || row > col)  rho[(size_t)col * D + row] = make_float2(re, -im);
            }
        }
}

// ---------------------------------------------------------------------------
__global__ void trace_inv(const float2* __restrict__ rho)
{
    __shared__ float red[256];
    float s = 0.f;
    for (int d = threadIdx.x; d < D; d += 256)
        s += rho[(size_t)d * (D + 1)].x;
    red[threadIdx.x] = s;
    __syncthreads();
    for (int off = 128; off > 0; off >>= 1) {
        if (threadIdx.x < off) red[threadIdx.x] += red[threadIdx.x + off];
        __syncthreads();
    }
    if (threadIdx.x == 0) g_inv_tr[0] = 1.0f / red[0];
}

// ---------------------------------------------------------------------------
// Staged 3-qubit contraction, stages c and b in place (verified in r4).
// Input x[j3*8+i3]; after this, x layout is [ja][sbH][sc][ia][sbL].
// ---------------------------------------------------------------------------
static __device__ __forceinline__ void qmt_stage_cb(float2* x,
                                                    const float* __restrict__ Mre,
                                                    const float* __restrict__ Mim)
{
    #pragma unroll
    for (int jj = 0; jj < 4; ++jj) {
        float2 y[16];
        #pragma unroll
        for (int sc = 0; sc < 4; ++sc)
            #pragma unroll
            for (int ii = 0; ii < 4; ++ii) {
                float2 acc = make_float2(0.f, 0.f);
                #pragma unroll
                for (int ic = 0; ic < 2; ++ic)
                    #pragma unroll
                    for (int jc = 0; jc < 2; ++jc) {
                        const float mr = Mre[sc * 4 + ic * 2 + jc];
                        const float mi = Mim[sc * 4 + ic * 2 + jc];
                        const float2 v = x[jj * 16 + jc * 8 + ii * 2 + ic];
                        acc.x += mr * v.x - mi * v.y;
                        acc.y += mr * v.y + mi * v.x;
                    }
                y[sc * 4 + ii] = acc;
            }
        #pragma unroll
        for (int q = 0; q < 16; ++q) x[jj * 16 + q] = y[q];
    }

    #pragma unroll
    for (int ja = 0; ja < 2; ++ja)
        #pragma unroll
        for (int sc = 0; sc < 4; ++sc) {
            float2 z[8];
            #pragma unroll
            for (int sb = 0; sb < 4; ++sb)
                #pragma unroll
                for (int ia = 0; ia < 2; ++ia) {
                    float2 acc = make_float2(0.f, 0.f);
                    #pragma unroll
                    for (int ib = 0; ib < 2; ++ib)
                        #pragma unroll
                        for (int jb = 0; jb < 2; ++jb) {
                            const float mr = Mre[sb * 4 + ib * 2 + jb];
                            const float mi = Mim[sb * 4 + ib * 2 + jb];
                            const float2 v = x[(ja * 2 + jb) * 16 + sc * 4 + ia * 2 + ib];
                            acc.x += mr * v.x - mi * v.y;
                            acc.y += mr * v.y + mi * v.x;
                        }
                    z[sb * 2 + ia] = acc;
                }
            #pragma unroll
            for (int sb = 0; sb < 4; ++sb)
                #pragma unroll
                for (int ia = 0; ia < 2; ++ia)
                    x[ja * 32 + (sb >> 1) * 16 + sc * 4 + ia * 2 + (sb & 1)] = z[sb * 2 + ia];
        }
}

// stage a: emits (s3, acc) pairs via the STORE statement.
#define QMT_STAGE_A(STORE)                                                     \
    _Pragma("unroll")                                                          \
    for (int sbH = 0; sbH < 2; ++sbH)                                          \
        _Pragma("unroll")                                                      \
        for (int sc = 0; sc < 4; ++sc)                                         \
            _Pragma("unroll")                                                  \
            for (int sbL = 0; sbL < 2; ++sbL) {                                \
                const int sb = sbH * 2 + sbL;                                  \
                _Pragma("unroll")                                              \
                for (int sa = 0; sa < 4; ++sa) {                               \
                    float2 acc = make_float2(0.f, 0.f);                        \
                    _Pragma("unroll")                                          \
                    for (int ia = 0; ia < 2; ++ia)                             \
                        _Pragma("unroll")                                      \
                        for (int ja = 0; ja < 2; ++ja) {                       \
                            const float mr = Mre[sa * 4 + ia * 2 + ja];        \
                            const float mi = Mim[sa * 4 + ia * 2 + ja];        \
                            const float2 v = x[ja * 32 + sbH * 16 + sc * 4 + ia * 2 + sbL]; \
                            acc.x += mr * v.x - mi * v.y;                      \
                            acc.y += mr * v.y + mi * v.x;                      \
                        }                                                      \
                    const int s3 = sa * 16 + sb * 4 + sc;                      \
                    STORE;                                                     \
                }                                                              \
            }

// ---------------------------------------------------------------------------
// Pass 1: contract LSB qubit triplet. in = rho [row(4096), col(4096)].
// out layout [r(512), c_hi(32), s3(64), c_lo(16)] -> 128-B store runs.
// ---------------------------------------------------------------------------
__global__ __launch_bounds__(256) void qmt_p1(const float2* __restrict__ in,
                                              float2* __restrict__ out,
                                              const float* __restrict__ Mre,
                                              const float* __restrict__ Mim)
{
    const int tid = blockIdx.x * 256 + threadIdx.x;   // 2^18
    const int c = tid & 511, r = tid >> 9;

    float2 x[64];
    #pragma unroll
    for (int j3 = 0; j3 < 8; ++j3) {
        const size_t base = (size_t)(r * 8 + j3) * 4096 + c * 8;
        #pragma unroll
        for (int i3 = 0; i3 < 8; ++i3) x[j3 * 8 + i3] = in[base + i3];
    }
    qmt_stage_cb(x, Mre, Mim);
    const size_t ob = (size_t)r * 32768 + (size_t)(c >> 4) * 1024 + (c & 15);
    QMT_STAGE_A(out[ob + s3 * 16] = acc)
}

// ---------------------------------------------------------------------------
// Pass 2: in layout [r'(512)=rr*8+j3, c_hi, s, c_lo] as written by p1.
// out [rr(64), cc(64), s3(64), s(64)] -> 512-B store runs.
// ---------------------------------------------------------------------------
__global__ __launch_bounds__(256) void qmt_p2(const float2* __restrict__ in,
                                              float2* __restrict__ out,
                                              const float* __restrict__ Mre,
                                              const float* __restrict__ Mim)
{
    const int tid = blockIdx.x * 256 + threadIdx.x;
    const int s = tid & 63, cc = (tid >> 6) & 63, rr = tid >> 12;

    float2 x[64];
    #pragma unroll
    for (int j3 = 0; j3 < 8; ++j3) {
        const size_t base = (size_t)(rr * 8 + j3) * 32768 +
                            (size_t)(cc >> 1) * 1024 + s * 16 + (cc & 1) * 8;
        #pragma unroll
        for (int i3 = 0; i3 < 8; ++i3) x[j3 * 8 + i3] = in[base + i3];
    }
    qmt_stage_cb(x, Mre, Mim);
    const size_t ob = ((size_t)(rr * 64 + cc)) * 4096 + s;
    QMT_STAGE_A(out[ob + s3 * 64] = acc)
}

// ---------------------------------------------------------------------------
// Pass 3: in [rr(64), cc(64), S(4096)]; out [r3(8), c3(8), s3(64), S(4096)].
// ---------------------------------------------------------------------------
__global__ __launch_bounds__(256) void qmt_p3(const float2* __restrict__ in,
                                              float2* __restrict__ out,
                                              const float* __restrict__ Mre,
                                              const float* __restrict__ Mim)
{
    const int tid = blockIdx.x * 256 + threadIdx.x;
    const int s = tid & 4095, c3 = (tid >> 12) & 7, r3 = tid >> 15;

    float2 x[64];
    #pragma unroll
    for (int j3 = 0; j3 < 8; ++j3)
        #pragma unroll
        for (int i3 = 0; i3 < 8; ++i3)
            x[j3 * 8 + i3] = in[(size_t)((r3 * 8 + j3) * 64 + c3 * 8 + i3) * 4096 + s];
    qmt_stage_cb(x, Mre, Mim);
    const size_t ob = ((size_t)(r3 * 8 + c3) * 64) * 4096 + s;
    QMT_STAGE_A(out[ob + s3 * 4096] = acc)
}

// ---------------------------------------------------------------------------
// Pass 4 (MSB triplet): in [j3(8), i3(8), S(262144)]; out REAL ONLY, layout
// [s_hi(8192), s3(64), s_lo(32)] floats -> 128-B store runs.
// ---------------------------------------------------------------------------
__global__ __launch_bounds__(256) void qmt_p4(const float2* __restrict__ in,
                                              float* __restrict__ out,
                                              const float* __restrict__ Mre,
                                              const float* __restrict__ Mim)
{
    const int tid = blockIdx.x * 256 + threadIdx.x;   // 2^18
    float2 x[64];
    #pragma unroll
    for (int j3 = 0; j3 < 8; ++j3)
        #pragma unroll
        for (int i3 = 0; i3 < 8; ++i3)
            x[j3 * 8 + i3] = in[(size_t)(j3 * 8 + i3) * 262144 + tid];
    qmt_stage_cb(x, Mre, Mim);
    const size_t ob = (size_t)(tid >> 5) * 2048 + (tid & 31);
    QMT_STAGE_A(out[ob + s3 * 32] = acc.x)
}

// ---------------------------------------------------------------------------
// Gather with the pass-4 permutation: idx = [s3(6 bits) | s(18 bits)],
// stored at (s>>5)*2048 + s3*32 + (s&31).
// ---------------------------------------------------------------------------
__global__ void gather_idx(const float* __restrict__ P, const int* __restrict__ idxs,
                           float* __restrict__ out, const int n)
{
    const int i = blockIdx.x * 256 + threadIdx.x;
    if (i < n) {
        const int idx = idxs[i];
        const int s = idx & 262143;
        const size_t pos = (size_t)(s >> 5) * 2048 + (size_t)(idx >> 18) * 32 + (s & 31);
        out[i] = P[pos] * g_inv_tr[0];
    }
}

// ---------------------------------------------------------------------------
extern "C" void kernel_launch(void* const* d_in, const int* in_sizes, int n_in,
                              void* d_out, int out_size, void* d_ws, size_t ws_size,
                              hipStream_t stream)
{
    const float* params = (const float*)d_in[0];  // (2, D, RANK) fp32
    const float* Mre    = (const float*)d_in[1];
    const float* Mim    = (const float*)d_in[2];
    const int*   idxs   = (const int*)d_in[3];
    float*       out    = (float*)d_out;

    float* ws = (float*)d_ws;
    float2* A  = (float2*)ws;                 // 134 MB plane
    float2* Bp = (float2*)(ws + 2 * NTOT);    // 134 MB plane
    unsigned short* Wh = (unsigned short*)Bp; // bf16 planes in dead B region
    unsigned short* Wl = Wh + 2 * UELEMS;

    convert_w<<<4096, 256, 0, stream>>>(params, Wh, Wl);
    gemm_rho_fused<<<1056, 256, 0, stream>>>(Wh, Wl, A);
    trace_inv<<<1, 256, 0, stream>>>(A);

    qmt_p1<<<1024, 256, 0, stream>>>(A, Bp, Mre, Mim);
    qmt_p2<<<1024, 256, 0, stream>>>(Bp, A, Mre, Mim);
    qmt_p3<<<1024, 256, 0, stream>>>(A, Bp, Mre, Mim);
    qmt_p4<<<1024, 256, 0, stream>>>(Bp, (float*)A, Mre, Mim);

    gather_idx<<<(out_size + 255) / 256, 256, 0, stream>>>((float*)A, idxs, out, out_size);
}

// Round 6
// 527.214 us; speedup vs baseline: 4.7472x; 1.1640x over previous
//
#include <hip/hip_runtime.h>

#define D 4096
#define RANK 1024
#define K2 2048
#define UELEMS 4194304ULL   // D*RANK
#define NTOT 16777216ULL    // 4^12 = D*D
#define QSCALE 16000.0f

typedef __attribute__((ext_vector_type(4))) int i32x4;

__device__ float g_inv_tr[1];
__device__ float g_scale[D];

static __device__ __forceinline__ void load_lds16(const void* g, void* l) {
    __builtin_amdgcn_global_load_lds(
        (const __attribute__((address_space(1))) unsigned int*)g,
        (__attribute__((address_space(3))) unsigned int*)l, 16, 0, 0);
}

// ---------------------------------------------------------------------------
// i8 split quantization of W = [Ur | Ui] with per-row scale.
// x ~= s_r*(128*h + l), h in [-125,125], l in [-64,64]; planes Wh,Wl (D x 2048)
// and NEGATED Ui-half planes N2h,N2l (D x 1024) for the im-part's -A1*B2 term.
// One wave per row; lane handles 16 Ur + 16 Ui elems.
// ---------------------------------------------------------------------------
__global__ __launch_bounds__(256) void convert_w_i8(const float* __restrict__ P,
                                                    char* __restrict__ Wh,
                                                    char* __restrict__ Wl,
                                                    char* __restrict__ N2h,
                                                    char* __restrict__ N2l)
{
    const int w = threadIdx.x >> 6, lane = threadIdx.x & 63;
    const int row = blockIdx.x * 4 + w;

    float ur[16], ui[16];
    const float* pr = P + (size_t)row * RANK + lane * 16;
    const float* pi = P + UELEMS + (size_t)row * RANK + lane * 16;
    #pragma unroll
    for (int q = 0; q < 4; ++q) {
        const float4 a = ((const float4*)pr)[q];
        const float4 b = ((const float4*)pi)[q];
        ur[q * 4 + 0] = a.x; ur[q * 4 + 1] = a.y; ur[q * 4 + 2] = a.z; ur[q * 4 + 3] = a.w;
        ui[q * 4 + 0] = b.x; ui[q * 4 + 1] = b.y; ui[q * 4 + 2] = b.z; ui[q * 4 + 3] = b.w;
    }
    float mx = 0.f;
    #pragma unroll
    for (int e = 0; e < 16; ++e)
        mx = fmaxf(mx, fmaxf(fabsf(ur[e]), fabsf(ui[e])));
    #pragma unroll
    for (int off = 1; off < 64; off <<= 1)
        mx = fmaxf(mx, __shfl_xor(mx, off));
    const float inv = mx > 0.f ? QSCALE / mx : 0.f;
    if (lane == 0) g_scale[row] = mx / QSCALE;

    int hr[16], lr[16], hi[16], li[16];
    #pragma unroll
    for (int e = 0; e < 16; ++e) {
        float q = ur[e] * inv;
        float hf = rintf(q * 0.0078125f);
        hr[e] = (int)hf; lr[e] = (int)rintf(q - 128.f * hf);
        q = ui[e] * inv;
        hf = rintf(q * 0.0078125f);
        hi[e] = (int)hf; li[e] = (int)rintf(q - 128.f * hf);
    }
    uint4 phr, plr, phi, pli, pnh, pnl;
    unsigned* dst[6] = {(unsigned*)&phr, (unsigned*)&plr, (unsigned*)&phi,
                        (unsigned*)&pli, (unsigned*)&pnh, (unsigned*)&pnl};
    #pragma unroll
    for (int q = 0; q < 4; ++q) {
        unsigned a = 0, b = 0, c = 0, d = 0, e = 0, f = 0;
        #pragma unroll
        for (int k = 0; k < 4; ++k) {
            const int sh = k * 8;
            a |= (unsigned)(hr[q * 4 + k] & 255) << sh;
            b |= (unsigned)(lr[q * 4 + k] & 255) << sh;
            c |= (unsigned)(hi[q * 4 + k] & 255) << sh;
            d |= (unsigned)(li[q * 4 + k] & 255) << sh;
            e |= (unsigned)((-hi[q * 4 + k]) & 255) << sh;
            f |= (unsigned)((-li[q * 4 + k]) & 255) << sh;
        }
        dst[0][q] = a; dst[1][q] = b; dst[2][q] = c; dst[3][q] = d; dst[4][q] = e; dst[5][q] = f;
    }
    const size_t b1 = (size_t)row * 2048 + lane * 16;
    *(uint4*)&Wh[b1] = phr;          *(uint4*)&Wl[b1] = plr;
    *(uint4*)&Wh[b1 + 1024] = phi;   *(uint4*)&Wl[b1 + 1024] = pli;
    const size_t b2 = (size_t)row * 1024 + lane * 16;
    *(uint4*)&N2h[b2] = pnh;         *(uint4*)&N2l[b2] = pnl;
}

// ---------------------------------------------------------------------------
// Fused Hermitian GEMM in i8: lower-triangle 64x128 tiles of rho (float2),
// mirror as conjugate. Per 64-k-step, 12 mfma_i32_16x16x64_i8 per (i,j):
//   re = A1*B1 + A2*B2 ; im = A2*B1 + A1*(-B2)   (hh and mix acc sets)
// val = s_r*s_c*(16384*hh + 128*mix). LDS 64 KB, 2 blocks/CU.
// ---------------------------------------------------------------------------
__global__ __launch_bounds__(256, 2) void gemm_rho_i8(const char* __restrict__ Wh,
                                                      const char* __restrict__ Wl,
                                                      const char* __restrict__ N2h,
                                                      const char* __restrict__ N2l,
                                                      float2* __restrict__ rho)
{
    __shared__ __align__(16) char sA1h[64 * 64];
    __shared__ __align__(16) char sA1l[64 * 64];
    __shared__ __align__(16) char sA2h[64 * 64];
    __shared__ __align__(16) char sA2l[64 * 64];
    __shared__ __align__(16) char sB1h[128 * 64];
    __shared__ __align__(16) char sB1l[128 * 64];
    __shared__ __align__(16) char sB2h[128 * 64];
    __shared__ __align__(16) char sB2l[128 * 64];
    __shared__ __align__(16) char sN2h[128 * 64];
    __shared__ __align__(16) char sN2l[128 * 64];

    const int b = blockIdx.x;
    int bj = (int)((65.0f - sqrtf(4225.0f - 4.0f * (float)b)) * 0.5f);
    while (bj > 0 && bj * (65 - bj) > b) --bj;
    while ((bj + 1) * (64 - bj) <= b) ++bj;
    const int bi = 2 * bj + (b - bj * (65 - bj));
    const int row0 = bi << 6, col0 = bj << 7;
    const bool full = (bi >= 2 * bj + 2);

    const int t = threadIdx.x;
    const int lane = t & 63, w = t >> 6;
    const int wr = w >> 1, wc = w & 1;

    // staging: 16-B granules, 4 per 64-B row-chunk, XOR swizzle (row>>1)&3
    const int rowA = t >> 2;
    const int kcA = (t & 3) ^ ((rowA >> 1) & 3);
    const size_t aoff = (size_t)(row0 + rowA) * 2048 + kcA * 16;
    const int ldsA = t * 16;
    size_t boff[2], boffN[2]; int ldsB[2];
    #pragma unroll
    for (int q = 0; q < 2; ++q) {
        const int g = q * 256 + t;
        const int rowB = g >> 2;
        const int kcB = (g & 3) ^ ((rowB >> 1) & 3);
        boff[q]  = (size_t)(col0 + rowB) * 2048 + kcB * 16;
        boffN[q] = (size_t)(col0 + rowB) * 1024 + kcB * 16;
        ldsB[q] = g * 16;
    }

    const int m = lane & 15, gq = lane >> 4;
    const int fko = (gq ^ ((m >> 1) & 3)) * 16;   // byte offset of k-chunk

    i32x4 rehh[2][4], remx[2][4], imhh[2][4], immx[2][4];
    #pragma unroll
    for (int i = 0; i < 2; ++i)
        #pragma unroll
        for (int j = 0; j < 4; ++j) {
            rehh[i][j] = (i32x4){0, 0, 0, 0}; remx[i][j] = (i32x4){0, 0, 0, 0};
            imhh[i][j] = (i32x4){0, 0, 0, 0}; immx[i][j] = (i32x4){0, 0, 0, 0};
        }

    for (int kt = 0; kt < RANK; kt += 64) {
        load_lds16(Wh + aoff + kt,        &sA1h[ldsA]);
        load_lds16(Wl + aoff + kt,        &sA1l[ldsA]);
        load_lds16(Wh + aoff + kt + 1024, &sA2h[ldsA]);
        load_lds16(Wl + aoff + kt + 1024, &sA2l[ldsA]);
        #pragma unroll
        for (int q = 0; q < 2; ++q) {
            load_lds16(Wh + boff[q] + kt,        &sB1h[ldsB[q]]);
            load_lds16(Wl + boff[q] + kt,        &sB1l[ldsB[q]]);
            load_lds16(Wh + boff[q] + kt + 1024, &sB2h[ldsB[q]]);
            load_lds16(Wl + boff[q] + kt + 1024, &sB2l[ldsB[q]]);
            load_lds16(N2h + boffN[q] + kt,      &sN2h[ldsB[q]]);
            load_lds16(N2l + boffN[q] + kt,      &sN2l[ldsB[q]]);
        }
        __syncthreads();

        i32x4 fa1h[2], fa1l[2], fa2h[2], fa2l[2];
        #pragma unroll
        for (int i = 0; i < 2; ++i) {
            const int off = (wr * 32 + i * 16 + m) * 64 + fko;
            fa1h[i] = *(const i32x4*)&sA1h[off];
            fa1l[i] = *(const i32x4*)&sA1l[off];
            fa2h[i] = *(const i32x4*)&sA2h[off];
            fa2l[i] = *(const i32x4*)&sA2l[off];
        }
        #pragma unroll
        for (int j = 0; j < 4; ++j) {
            const int off = (wc * 64 + j * 16 + m) * 64 + fko;
            const i32x4 b1h = *(const i32x4*)&sB1h[off];
            const i32x4 b1l = *(const i32x4*)&sB1l[off];
            const i32x4 b2h = *(const i32x4*)&sB2h[off];
            const i32x4 b2l = *(const i32x4*)&sB2l[off];
            const i32x4 n2h = *(const i32x4*)&sN2h[off];
            const i32x4 n2l = *(const i32x4*)&sN2l[off];
            #pragma unroll
            for (int i = 0; i < 2; ++i) {
                i32x4 r = rehh[i][j];
                r = __builtin_amdgcn_mfma_i32_16x16x64_i8(fa1h[i], b1h, r, 0, 0, 0);
                r = __builtin_amdgcn_mfma_i32_16x16x64_i8(fa2h[i], b2h, r, 0, 0, 0);
                rehh[i][j] = r;
                r = remx[i][j];
                r = __builtin_amdgcn_mfma_i32_16x16x64_i8(fa1h[i], b1l, r, 0, 0, 0);
                r = __builtin_amdgcn_mfma_i32_16x16x64_i8(fa1l[i], b1h, r, 0, 0, 0);
                r = __builtin_amdgcn_mfma_i32_16x16x64_i8(fa2h[i], b2l, r, 0, 0, 0);
                r = __builtin_amdgcn_mfma_i32_16x16x64_i8(fa2l[i], b2h, r, 0, 0, 0);
                remx[i][j] = r;
                r = imhh[i][j];
                r = __builtin_amdgcn_mfma_i32_16x16x64_i8(fa2h[i], b1h, r, 0, 0, 0);
                r = __builtin_amdgcn_mfma_i32_16x16x64_i8(fa1h[i], n2h, r, 0, 0, 0);
                imhh[i][j] = r;
                r = immx[i][j];
                r = __builtin_amdgcn_mfma_i32_16x16x64_i8(fa2h[i], b1l, r, 0, 0, 0);
                r = __builtin_amdgcn_mfma_i32_16x16x64_i8(fa2l[i], b1h, r, 0, 0, 0);
                r = __builtin_amdgcn_mfma_i32_16x16x64_i8(fa1h[i], n2l, r, 0, 0, 0);
                r = __builtin_amdgcn_mfma_i32_16x16x64_i8(fa1l[i], n2h, r, 0, 0, 0);
                immx[i][j] = r;
            }
        }
        __syncthreads();
    }

    // C/D layout: col = lane&15, row = (lane>>4)*4 + reg
    #pragma unroll
    for (int i = 0; i < 2; ++i)
        #pragma unroll
        for (int j = 0; j < 4; ++j) {
            const int col = col0 + wc * 64 + j * 16 + m;
            const float sc = g_scale[col];
            #pragma unroll
            for (int r = 0; r < 4; ++r) {
                const int row = row0 + wr * 32 + i * 16 + gq * 4 + r;
                const float s2 = g_scale[row] * sc;
                const float re = s2 * (16384.f * (float)rehh[i][j][r] + 128.f * (float)remx[i][j][r]);
                const float im = s2 * (16384.f * (float)imhh[i][j][r] + 128.f * (float)immx[i][j][r]);
                if (full || row >= col) rho[(size_t)row * D + col] = make_float2(re, im);
                if (full || row > col)  rho[(size_t)col * D + row] = make_float2(re, -im);
            }
        }
}

// ---------------------------------------------------------------------------
__global__ void trace_inv(const float2* __restrict__ rho)
{
    __shared__ float red[256];
    float s = 0.f;
    for (int d = threadIdx.x; d < D; d += 256)
        s += rho[(size_t)d * (D + 1)].x;
    red[threadIdx.x] = s;
    __syncthreads();
    for (int off = 128; off > 0; off >>= 1) {
        if (threadIdx.x < off) red[threadIdx.x] += red[threadIdx.x + off];
        __syncthreads();
    }
    if (threadIdx.x == 0) g_inv_tr[0] = 1.0f / red[0];
}

// ---------------------------------------------------------------------------
// Staged 3-qubit contraction, stages c and b in place (verified r4/r5).
// ---------------------------------------------------------------------------
static __device__ __forceinline__ void qmt_stage_cb(float2* x,
                                                    const float* __restrict__ Mre,
                                                    const float* __restrict__ Mim)
{
    #pragma unroll
    for (int jj = 0; jj < 4; ++jj) {
        float2 y[16];
        #pragma unroll
        for (int sc = 0; sc < 4; ++sc)
            #pragma unroll
            for (int ii = 0; ii < 4; ++ii) {
                float2 acc = make_float2(0.f, 0.f);
                #pragma unroll
                for (int ic = 0; ic < 2; ++ic)
                    #pragma unroll
                    for (int jc = 0; jc < 2; ++jc) {
                        const float mr = Mre[sc * 4 + ic * 2 + jc];
                        const float mi = Mim[sc * 4 + ic * 2 + jc];
                        const float2 v = x[jj * 16 + jc * 8 + ii * 2 + ic];
                        acc.x += mr * v.x - mi * v.y;
                        acc.y += mr * v.y + mi * v.x;
                    }
                y[sc * 4 + ii] = acc;
            }
        #pragma unroll
        for (int q = 0; q < 16; ++q) x[jj * 16 + q] = y[q];
    }

    #pragma unroll
    for (int ja = 0; ja < 2; ++ja)
        #pragma unroll
        for (int sc = 0; sc < 4; ++sc) {
            float2 z[8];
            #pragma unroll
            for (int sb = 0; sb < 4; ++sb)
                #pragma unroll
                for (int ia = 0; ia < 2; ++ia) {
                    float2 acc = make_float2(0.f, 0.f);
                    #pragma unroll
                    for (int ib = 0; ib < 2; ++ib)
                        #pragma unroll
                        for (int jb = 0; jb < 2; ++jb) {
                            const float mr = Mre[sb * 4 + ib * 2 + jb];
                            const float mi = Mim[sb * 4 + ib * 2 + jb];
                            const float2 v = x[(ja * 2 + jb) * 16 + sc * 4 + ia * 2 + ib];
                            acc.x += mr * v.x - mi * v.y;
                            acc.y += mr * v.y + mi * v.x;
                        }
                    z[sb * 2 + ia] = acc;
                }
            #pragma unroll
            for (int sb = 0; sb < 4; ++sb)
                #pragma unroll
                for (int ia = 0; ia < 2; ++ia)
                    x[ja * 32 + (sb >> 1) * 16 + sc * 4 + ia * 2 + (sb & 1)] = z[sb * 2 + ia];
        }
}

#define QMT_STAGE_A(STORE)                                                     \
    _Pragma("unroll")                                                          \
    for (int sbH = 0; sbH < 2; ++sbH)                                          \
        _Pragma("unroll")                                                      \
        for (int sc = 0; sc < 4; ++sc)                                         \
            _Pragma("unroll")                                                  \
            for (int sbL = 0; sbL < 2; ++sbL) {                                \
                const int sb = sbH * 2 + sbL;                                  \
                _Pragma("unroll")                                              \
                for (int sa = 0; sa < 4; ++sa) {                               \
                    float2 acc = make_float2(0.f, 0.f);                        \
                    _Pragma("unroll")                                          \
                    for (int ia = 0; ia < 2; ++ia)                             \
                        _Pragma("unroll")                                      \
                        for (int ja = 0; ja < 2; ++ja) {                       \
                            const float mr = Mre[sa * 4 + ia * 2 + ja];        \
                            const float mi = Mim[sa * 4 + ia * 2 + ja];        \
                            const float2 v = x[ja * 32 + sbH * 16 + sc * 4 + ia * 2 + sbL]; \
                            acc.x += mr * v.x - mi * v.y;                      \
                            acc.y += mr * v.y + mi * v.x;                      \
                        }                                                      \
                    const int s3 = sa * 16 + sb * 4 + sc;                      \
                    STORE;                                                     \
                }                                                              \
            }

// ---------------------------------------------------------------------------
__global__ __launch_bounds__(256) void qmt_p1(const float2* __restrict__ in,
                                              float2* __restrict__ out,
                                              const float* __restrict__ Mre,
                                              const float* __restrict__ Mim)
{
    const int tid = blockIdx.x * 256 + threadIdx.x;   // 2^18
    const int c = tid & 511, r = tid >> 9;

    float2 x[64];
    #pragma unroll
    for (int j3 = 0; j3 < 8; ++j3) {
        const size_t base = (size_t)(r * 8 + j3) * 4096 + c * 8;
        #pragma unroll
        for (int i3 = 0; i3 < 8; ++i3) x[j3 * 8 + i3] = in[base + i3];
    }
    qmt_stage_cb(x, Mre, Mim);
    const size_t ob = (size_t)r * 32768 + (size_t)(c >> 4) * 1024 + (c & 15);
    QMT_STAGE_A(out[ob + s3 * 16] = acc)
}

__global__ __launch_bounds__(256) void qmt_p2(const float2* __restrict__ in,
                                              float2* __restrict__ out,
                                              const float* __restrict__ Mre,
                                              const float* __restrict__ Mim)
{
    const int tid = blockIdx.x * 256 + threadIdx.x;
    const int s = tid & 63, cc = (tid >> 6) & 63, rr = tid >> 12;

    float2 x[64];
    #pragma unroll
    for (int j3 = 0; j3 < 8; ++j3) {
        const size_t base = (size_t)(rr * 8 + j3) * 32768 +
                            (size_t)(cc >> 1) * 1024 + s * 16 + (cc & 1) * 8;
        #pragma unroll
        for (int i3 = 0; i3 < 8; ++i3) x[j3 * 8 + i3] = in[base + i3];
    }
    qmt_stage_cb(x, Mre, Mim);
    const size_t ob = ((size_t)(rr * 64 + cc)) * 4096 + s;
    QMT_STAGE_A(out[ob + s3 * 64] = acc)
}

__global__ __launch_bounds__(256) void qmt_p3(const float2* __restrict__ in,
                                              float2* __restrict__ out,
                                              const float* __restrict__ Mre,
                                              const float* __restrict__ Mim)
{
    const int tid = blockIdx.x * 256 + threadIdx.x;
    const int s = tid & 4095, c3 = (tid >> 12) & 7, r3 = tid >> 15;

    float2 x[64];
    #pragma unroll
    for (int j3 = 0; j3 < 8; ++j3)
        #pragma unroll
        for (int i3 = 0; i3 < 8; ++i3)
            x[j3 * 8 + i3] = in[(size_t)((r3 * 8 + j3) * 64 + c3 * 8 + i3) * 4096 + s];
    qmt_stage_cb(x, Mre, Mim);
    const size_t ob = ((size_t)(r3 * 8 + c3) * 64) * 4096 + s;
    QMT_STAGE_A(out[ob + s3 * 4096] = acc)
}

__global__ __launch_bounds__(256) void qmt_p4(const float2* __restrict__ in,
                                              float* __restrict__ out,
                                              const float* __restrict__ Mre,
                                              const float* __restrict__ Mim)
{
    const int tid = blockIdx.x * 256 + threadIdx.x;   // 2^18
    float2 x[64];
    #pragma unroll
    for (int j3 = 0; j3 < 8; ++j3)
        #pragma unroll
        for (int i3 = 0; i3 < 8; ++i3)
            x[j3 * 8 + i3] = in[(size_t)(j3 * 8 + i3) * 262144 + tid];
    qmt_stage_cb(x, Mre, Mim);
    const size_t ob = (size_t)(tid >> 5) * 2048 + (tid & 31);
    QMT_STAGE_A(out[ob + s3 * 32] = acc.x)
}

// ---------------------------------------------------------------------------
__global__ void gather_idx(const float* __restrict__ P, const int* __restrict__ idxs,
                           float* __restrict__ out, const int n)
{
    const int i = blockIdx.x * 256 + threadIdx.x;
    if (i < n) {
        const int idx = idxs[i];
        const int s = idx & 262143;
        const size_t pos = (size_t)(s >> 5) * 2048 + (size_t)(idx >> 18) * 32 + (s & 31);
        out[i] = P[pos] * g_inv_tr[0];
    }
}

// ---------------------------------------------------------------------------
extern "C" void kernel_launch(void* const* d_in, const int* in_sizes, int n_in,
                              void* d_out, int out_size, void* d_ws, size_t ws_size,
                              hipStream_t stream)
{
    const float* params = (const float*)d_in[0];  // (2, D, RANK) fp32
    const float* Mre    = (const float*)d_in[1];
    const float* Mim    = (const float*)d_in[2];
    const int*   idxs   = (const int*)d_in[3];
    float*       out    = (float*)d_out;

    float* ws = (float*)d_ws;
    float2* A  = (float2*)ws;                 // 134 MB plane
    float2* Bp = (float2*)(ws + 2 * NTOT);    // 134 MB plane
    // i8 planes in the (dead until pass 0) B region: 8.4+8.4+4.2+4.2 = 25 MB
    char* Wh  = (char*)Bp;
    char* Wl  = Wh + (size_t)D * 2048;
    char* N2h = Wl + (size_t)D * 2048;
    char* N2l = N2h + (size_t)D * 1024;

    convert_w_i8<<<1024, 256, 0, stream>>>(params, Wh, Wl, N2h, N2l);
    gemm_rho_i8<<<1056, 256, 0, stream>>>(Wh, Wl, N2h, N2l, A);
    trace_inv<<<1, 256, 0, stream>>>(A);

    qmt_p1<<<1024, 256, 0, stream>>>(A, Bp, Mre, Mim);
    qmt_p2<<<1024, 256, 0, stream>>>(Bp, A, Mre, Mim);
    qmt_p3<<<1024, 256, 0, stream>>>(A, Bp, Mre, Mim);
    qmt_p4<<<1024, 256, 0, stream>>>(Bp, (float*)A, Mre, Mim);

    gather_idx<<<(out_size + 255) / 256, 256, 0, stream>>>((float*)A, idxs, out, out_size);
}